// Round 1
// baseline (402.406 us; speedup 1.0000x reference)
//
#include <hip/hip_runtime.h>
#include <math.h>

#define HH 1024
#define WW 1024
#define NB 32
#define TS 64
#define IMG (HH * WW)
#define HROWS 94          // TS + 2*15
#define HSTR 68           // hrow LDS stride (68%32=4 spreads phase-1 write banks)
#define NT 4              // tiles per block
#define NBLK 2048         // 8192 tiles / NT
#define TILES_PER_IMG 256
#define NSLOT (NB * TILES_PER_IMG)

// LDS-only barrier: orders ds ops without draining vmcnt -> prefetch loads
// stay in flight across it (the __syncthreads vmcnt(0) drain was the stall).
#define RAW_BARRIER() asm volatile("s_waitcnt lgkmcnt(0)\n\ts_barrier" ::: "memory")

// ws layout (floats): bceP[8192] | intP[8192] | uniP[8192]

// Halo rows of tgt for one 64x64 tile: threads 0..187 = (row 0..93) x (half 0,1),
// each holds 64 floats (16 float4). OOB regions are whole-float4 aligned, so
// clamp-address + mask replaces the divergent edge path. Caller guards tid<188.
__device__ __forceinline__ void load_f(const float* __restrict__ tb,
                                       int r0, int c0, int tid, float fs[64])
{
  int rh = tid >> 1, h = tid & 1;
  int gr = r0 - 15 + rh;
  int grc = min(max(gr, 0), HH - 1);
  bool rowOK = ((unsigned)gr < (unsigned)HH);
  int cb = c0 + h * 32 - 16;
  const float* rowp = tb + (size_t)grc * WW;
  #pragma unroll
  for (int u = 0; u < 16; ++u) {
    int colb = cb + 4 * u;
    bool ok = rowOK && (colb >= 0) && (colb <= WW - 4);
    int colc = min(max(colb, 0), WW - 4);
    float4 q = *(const float4*)(rowp + colc);
    fs[4 * u + 0] = ok ? q.x : 0.f;
    fs[4 * u + 1] = ok ? q.y : 0.f;
    fs[4 * u + 2] = ok ? q.z : 0.f;
    fs[4 * u + 3] = ok ? q.w : 0.f;
  }
}

// inp pixels for one tile in phase-2 layout: thread = (col 0..63) x (rowgroup 0..3).
// Issued between phase 1 and the LDS-only barrier: the 16 loads stay in flight
// across s_barrier and land under the phase-2 vertical-sum preamble.
__device__ __forceinline__ void load_x(const float* __restrict__ ib,
                                       int r0, int c0, int tid, float xv[16])
{
  int c = tid & 63, rt0 = (tid >> 6) * 16;
  const float* p = ib + (size_t)(r0 + rt0) * WW + (c0 + c);
  #pragma unroll
  for (int j = 0; j < 16; ++j)
    xv[j] = __builtin_nontemporal_load(&p[(size_t)j * WW]);
}

// TLP over ILP: no cross-tile register prefetch. fs[64] is scoped to phase 1
// (dead before phase 2), xv[16] is the only state across the mid-tile barrier.
// Peak live set ~72 VGPRs -> 6 blocks/CU (LDS: 6*26112 = 153KB <= 160KB).
__global__ __launch_bounds__(256, 6) void wloss_main(
    const float* __restrict__ inp, const float* __restrict__ tgt,
    float* __restrict__ ws)
{
  __shared__ float hrow[HROWS * HSTR]; // 94*68*4 = 25568 B
  __shared__ float red[12];

  const int tid = threadIdx.x;
  const int k = blockIdx.x;            // 0..NBLK-1

  #pragma unroll
  for (int it = 0; it < NT; ++it) {
    const int tile = k + it * NBLK;
    const int b = tile >> 8, ty = (tile >> 4) & 15, tx = tile & 15;
    const int r0 = ty * TS, c0 = tx * TS;
    const float* tb = tgt + (size_t)b * IMG;

    // ---- phase 1: load halo + 31-wide horizontal sliding sums -> hrow ----
    // Write-as-you-go (float4 every 4 outputs): no out[32] array, fs dies here.
    if (tid < 188) {
      float fs[64];
      load_f(tb, r0, c0, tid, fs);
      int rh = tid >> 1, h = tid & 1;
      float a0 = 0.f, a1 = 0.f, a2 = 0.f, a3 = 0.f;
      #pragma unroll
      for (int i = 1; i <= 25; i += 4) {
        a0 += fs[i]; a1 += fs[i + 1]; a2 += fs[i + 2]; a3 += fs[i + 3];
      }
      float s = (a0 + a1) + (a2 + a3) + fs[29] + fs[30] + fs[31];
      float* hp = &hrow[rh * HSTR + h * 32];
      #pragma unroll
      for (int g = 0; g < 8; ++g) {
        float o0, o1, o2, o3;
        if (g == 0) { o0 = s; }
        else       { s += fs[4 * g + 31] - fs[4 * g]; o0 = s; }
        s += fs[4 * g + 32] - fs[4 * g + 1]; o1 = s;
        s += fs[4 * g + 33] - fs[4 * g + 2]; o2 = s;
        s += fs[4 * g + 34] - fs[4 * g + 3]; o3 = s;
        *(float4*)&hp[4 * g] = make_float4(o0, o1, o2, o3);
      }
    }

    // ---- issue inp loads for THIS tile; they ride across the barrier ----
    float xv[16];
    load_x(inp + (size_t)b * IMG, r0, c0, tid, xv);

    RAW_BARRIER();   // hrow write -> read; vmem stays in flight

    // ---- phase 2: vertical 31-slide + loss math ----
    const int c = tid & 63;
    const int rt0 = (tid >> 6) * 16;
    float vs;
    {
      float a0 = 0.f, a1 = 0.f, a2 = 0.f, a3 = 0.f;
      #pragma unroll
      for (int kk = 0; kk < 28; kk += 4) {
        a0 += hrow[(rt0 + kk    ) * HSTR + c];
        a1 += hrow[(rt0 + kk + 1) * HSTR + c];
        a2 += hrow[(rt0 + kk + 2) * HSTR + c];
        a3 += hrow[(rt0 + kk + 3) * HSTR + c];
      }
      vs = (a0 + a1) + (a2 + a3)
         + hrow[(rt0 + 28) * HSTR + c] + hrow[(rt0 + 29) * HSTR + c]
         + hrow[(rt0 + 30) * HSTR + c];
    }

    float a_bce = 0.f, a_int = 0.f, a_uni = 0.f;
    #pragma unroll 4
    for (int j = 0; j < 16; ++j) {
      if (j) vs += hrow[(rt0 + j + 30) * HSTR + c] - hrow[(rt0 + j - 1) * HSTR + c];
      float t = tb[(size_t)(r0 + rt0 + j) * WW + (c0 + c)];  // L1/L2-hot (phase-1 touched)
      float x = xv[j];
      float w = fmaf(5.f, fabsf(vs * (1.f / 961.f) - t), 1.f);
      float ax  = fabsf(x);
      float e   = __expf(-ax);
      float inv = __fdividef(1.f, 1.f + e);
      float p   = (x >= 0.f) ? inv : e * inv;   // sigmoid from exp(-|x|)
      a_bce += fmaxf(x, 0.f) - x * t + __logf(1.f + e);
      a_int  = fmaf(p * t, w, a_int);
      a_uni  = fmaf(p + t, w, a_uni);
    }

    // ---- block reduction ----
    #pragma unroll
    for (int off = 32; off > 0; off >>= 1) {
      a_bce += __shfl_down(a_bce, off);
      a_int += __shfl_down(a_int, off);
      a_uni += __shfl_down(a_uni, off);
    }
    int wave = tid >> 6;
    if ((tid & 63) == 0) {
      red[wave * 3 + 0] = a_bce;
      red[wave * 3 + 1] = a_int;
      red[wave * 3 + 2] = a_uni;
    }
    RAW_BARRIER();   // red write -> read; also fences hrow reuse next iter
    if (tid == 0) {
      float sb = 0.f, si = 0.f, su = 0.f;
      #pragma unroll
      for (int wv = 0; wv < 4; ++wv) {
        sb += red[wv * 3 + 0];
        si += red[wv * 3 + 1];
        su += red[wv * 3 + 2];
      }
      ws[tile]             = sb;
      ws[NSLOT + tile]     = si;
      ws[2 * NSLOT + tile] = su;
    }
  }
}

__global__ __launch_bounds__(1024) void wloss_final(
    const float* __restrict__ ws, float* __restrict__ out)
{
  const float* bceP = ws;
  const float* intP = ws + NSLOT;
  const float* uniP = ws + 2 * NSLOT;
  __shared__ float sB[16];
  __shared__ float sI[NB], sU[NB];

  const int t = threadIdx.x;

  float bsum = 0.f;
  #pragma unroll
  for (int kk = 0; kk < 8; ++kk) bsum += bceP[t + kk * 1024];

  const int img = t >> 5, j = t & 31;
  const float* ip = intP + img * TILES_PER_IMG;
  const float* up = uniP + img * TILES_PER_IMG;
  float vi = 0.f, vu = 0.f;
  #pragma unroll
  for (int kk = 0; kk < 8; ++kk) { vi += ip[j + 32 * kk]; vu += up[j + 32 * kk]; }

  #pragma unroll
  for (int off = 32; off > 0; off >>= 1) bsum += __shfl_down(bsum, off, 64);
  #pragma unroll
  for (int off = 16; off > 0; off >>= 1) {
    vi += __shfl_down(vi, off, 32);
    vu += __shfl_down(vu, off, 32);
  }
  if ((t & 63) == 0) sB[t >> 6] = bsum;
  if (j == 0) { sI[img] = vi; sU[img] = vu; }
  __syncthreads();

  if (t == 0) {
    double bt = 0.0;
    #pragma unroll
    for (int wv = 0; wv < 16; ++wv) bt += (double)sB[wv];
    double bce = bt / ((double)NB * HH * WW);
    double s = 0.0;
    for (int b = 0; b < NB; ++b) {
      double inter = (double)sI[b];
      double uni   = (double)sU[b];
      double wiou  = 1.0 - (inter + 1.0) / (uni - inter + 1.0);
      s += bce + wiou;   // wbce[b,c] == bce exactly (scalar * weit, renormalized)
    }
    out[0] = (float)(s / NB);
  }
}

extern "C" void kernel_launch(void* const* d_in, const int* in_sizes, int n_in,
                              void* d_out, int out_size, void* d_ws, size_t ws_size,
                              hipStream_t stream)
{
  const float* inp = (const float*)d_in[0];
  const float* tgt = (const float*)d_in[1];
  float* ws = (float*)d_ws;   // 3*8192 floats = 96 KB; fully written each launch

  wloss_main<<<NBLK, 256, 0, stream>>>(inp, tgt, ws);
  wloss_final<<<1, 1024, 0, stream>>>(ws, (float*)d_out);
}

// Round 2
// 331.733 us; speedup vs baseline: 1.2130x; 1.2130x over previous
//
#include <hip/hip_runtime.h>
#include <math.h>

#define HH 1024
#define WW 1024
#define NB 32
#define TS 64
#define IMG (HH * WW)
#define HROWS 94          // TS + 2*15
#define HSTR 68           // hrow LDS stride (68%32=4 spreads phase-1 write banks)
#define NT 4              // tiles per block
#define NBLK 2048         // 8192 tiles / NT
#define TILES_PER_IMG 256
#define NSLOT (NB * TILES_PER_IMG)

// LDS-only barrier: orders ds ops without draining vmcnt -> prefetch loads
// stay in flight across it (the __syncthreads vmcnt(0) drain was the stall).
#define RAW_BARRIER() asm volatile("s_waitcnt lgkmcnt(0)\n\ts_barrier" ::: "memory")

// ws layout (floats): bceP[8192] | intP[8192] | uniP[8192]

// Halo rows of tgt for one 64x64 tile: threads 0..187 = (row 0..93) x (half 0,1),
// each holds 64 floats (16 float4). OOB regions are whole-float4 aligned, so
// clamp-address + mask replaces the divergent edge path. Caller guards tid<188.
__device__ __forceinline__ void load_f(const float* __restrict__ tb,
                                       int r0, int c0, int tid, float fs[64])
{
  int rh = tid >> 1, h = tid & 1;
  int gr = r0 - 15 + rh;
  int grc = min(max(gr, 0), HH - 1);
  bool rowOK = ((unsigned)gr < (unsigned)HH);
  int cb = c0 + h * 32 - 16;
  const float* rowp = tb + (size_t)grc * WW;
  #pragma unroll
  for (int u = 0; u < 16; ++u) {
    int colb = cb + 4 * u;
    bool ok = rowOK && (colb >= 0) && (colb <= WW - 4);
    int colc = min(max(colb, 0), WW - 4);
    float4 q = *(const float4*)(rowp + colc);
    fs[4 * u + 0] = ok ? q.x : 0.f;
    fs[4 * u + 1] = ok ? q.y : 0.f;
    fs[4 * u + 2] = ok ? q.z : 0.f;
    fs[4 * u + 3] = ok ? q.w : 0.f;
  }
}

// inp pixels for one tile in phase-2 layout: thread = (col 0..63) x (rowgroup 0..3).
// Issued between phase 1 and the LDS-only barrier: the 16 loads stay in flight
// across s_barrier and land under the phase-2 vertical-sum preamble.
__device__ __forceinline__ void load_x(const float* __restrict__ ib,
                                       int r0, int c0, int tid, float xv[16])
{
  int c = tid & 63, rt0 = (tid >> 6) * 16;
  const float* p = ib + (size_t)(r0 + rt0) * WW + (c0 + c);
  #pragma unroll
  for (int j = 0; j < 16; ++j)
    xv[j] = __builtin_nontemporal_load(&p[(size_t)j * WW]);
}

// TLP over ILP, but with a VGPR cap the live set actually fits:
// phase-1 live set is ~90-100 regs (fs[64] + in-flight float4s + addressing).
// (256,6) capped at 85 -> 15 floats/thread spilled, 127MB scratch writes
// (round-1 post-mortem). (256,4) caps at 128: no spill, 4 blocks/CU
// (16 waves/CU, LDS 4*26112 = 104KB <= 160KB) vs round-0's 3.
__global__ __launch_bounds__(256, 4) void wloss_main(
    const float* __restrict__ inp, const float* __restrict__ tgt,
    float* __restrict__ ws)
{
  __shared__ float hrow[HROWS * HSTR]; // 94*68*4 = 25568 B
  __shared__ float red[12];

  const int tid = threadIdx.x;
  const int k = blockIdx.x;            // 0..NBLK-1

  #pragma unroll
  for (int it = 0; it < NT; ++it) {
    const int tile = k + it * NBLK;
    const int b = tile >> 8, ty = (tile >> 4) & 15, tx = tile & 15;
    const int r0 = ty * TS, c0 = tx * TS;
    const float* tb = tgt + (size_t)b * IMG;

    // ---- phase 1: load halo + 31-wide horizontal sliding sums -> hrow ----
    // Write-as-you-go (float4 every 4 outputs): no out[32] array, fs dies here.
    if (tid < 188) {
      float fs[64];
      load_f(tb, r0, c0, tid, fs);
      int rh = tid >> 1, h = tid & 1;
      float a0 = 0.f, a1 = 0.f, a2 = 0.f, a3 = 0.f;
      #pragma unroll
      for (int i = 1; i <= 25; i += 4) {
        a0 += fs[i]; a1 += fs[i + 1]; a2 += fs[i + 2]; a3 += fs[i + 3];
      }
      float s = (a0 + a1) + (a2 + a3) + fs[29] + fs[30] + fs[31];
      float* hp = &hrow[rh * HSTR + h * 32];
      #pragma unroll
      for (int g = 0; g < 8; ++g) {
        float o0, o1, o2, o3;
        if (g == 0) { o0 = s; }
        else       { s += fs[4 * g + 31] - fs[4 * g]; o0 = s; }
        s += fs[4 * g + 32] - fs[4 * g + 1]; o1 = s;
        s += fs[4 * g + 33] - fs[4 * g + 2]; o2 = s;
        s += fs[4 * g + 34] - fs[4 * g + 3]; o3 = s;
        *(float4*)&hp[4 * g] = make_float4(o0, o1, o2, o3);
      }
    }

    // ---- issue inp loads for THIS tile; they ride across the barrier ----
    float xv[16];
    load_x(inp + (size_t)b * IMG, r0, c0, tid, xv);

    RAW_BARRIER();   // hrow write -> read; vmem stays in flight

    // ---- phase 2: vertical 31-slide + loss math ----
    const int c = tid & 63;
    const int rt0 = (tid >> 6) * 16;
    float vs;
    {
      float a0 = 0.f, a1 = 0.f, a2 = 0.f, a3 = 0.f;
      #pragma unroll
      for (int kk = 0; kk < 28; kk += 4) {
        a0 += hrow[(rt0 + kk    ) * HSTR + c];
        a1 += hrow[(rt0 + kk + 1) * HSTR + c];
        a2 += hrow[(rt0 + kk + 2) * HSTR + c];
        a3 += hrow[(rt0 + kk + 3) * HSTR + c];
      }
      vs = (a0 + a1) + (a2 + a3)
         + hrow[(rt0 + 28) * HSTR + c] + hrow[(rt0 + 29) * HSTR + c]
         + hrow[(rt0 + 30) * HSTR + c];
    }

    float a_bce = 0.f, a_int = 0.f, a_uni = 0.f;
    #pragma unroll 4
    for (int j = 0; j < 16; ++j) {
      if (j) vs += hrow[(rt0 + j + 30) * HSTR + c] - hrow[(rt0 + j - 1) * HSTR + c];
      float t = tb[(size_t)(r0 + rt0 + j) * WW + (c0 + c)];  // L1/L2-hot (phase-1 touched)
      float x = xv[j];
      float w = fmaf(5.f, fabsf(vs * (1.f / 961.f) - t), 1.f);
      float ax  = fabsf(x);
      float e   = __expf(-ax);
      float inv = __fdividef(1.f, 1.f + e);
      float p   = (x >= 0.f) ? inv : e * inv;   // sigmoid from exp(-|x|)
      a_bce += fmaxf(x, 0.f) - x * t + __logf(1.f + e);
      a_int  = fmaf(p * t, w, a_int);
      a_uni  = fmaf(p + t, w, a_uni);
    }

    // ---- block reduction ----
    #pragma unroll
    for (int off = 32; off > 0; off >>= 1) {
      a_bce += __shfl_down(a_bce, off);
      a_int += __shfl_down(a_int, off);
      a_uni += __shfl_down(a_uni, off);
    }
    int wave = tid >> 6;
    if ((tid & 63) == 0) {
      red[wave * 3 + 0] = a_bce;
      red[wave * 3 + 1] = a_int;
      red[wave * 3 + 2] = a_uni;
    }
    RAW_BARRIER();   // red write -> read; also fences hrow reuse next iter
    if (tid == 0) {
      float sb = 0.f, si = 0.f, su = 0.f;
      #pragma unroll
      for (int wv = 0; wv < 4; ++wv) {
        sb += red[wv * 3 + 0];
        si += red[wv * 3 + 1];
        su += red[wv * 3 + 2];
      }
      ws[tile]             = sb;
      ws[NSLOT + tile]     = si;
      ws[2 * NSLOT + tile] = su;
    }
  }
}

__global__ __launch_bounds__(1024) void wloss_final(
    const float* __restrict__ ws, float* __restrict__ out)
{
  const float* bceP = ws;
  const float* intP = ws + NSLOT;
  const float* uniP = ws + 2 * NSLOT;
  __shared__ float sB[16];
  __shared__ float sI[NB], sU[NB];

  const int t = threadIdx.x;

  float bsum = 0.f;
  #pragma unroll
  for (int kk = 0; kk < 8; ++kk) bsum += bceP[t + kk * 1024];

  const int img = t >> 5, j = t & 31;
  const float* ip = intP + img * TILES_PER_IMG;
  const float* up = uniP + img * TILES_PER_IMG;
  float vi = 0.f, vu = 0.f;
  #pragma unroll
  for (int kk = 0; kk < 8; ++kk) { vi += ip[j + 32 * kk]; vu += up[j + 32 * kk]; }

  #pragma unroll
  for (int off = 32; off > 0; off >>= 1) bsum += __shfl_down(bsum, off, 64);
  #pragma unroll
  for (int off = 16; off > 0; off >>= 1) {
    vi += __shfl_down(vi, off, 32);
    vu += __shfl_down(vu, off, 32);
  }
  if ((t & 63) == 0) sB[t >> 6] = bsum;
  if (j == 0) { sI[img] = vi; sU[img] = vu; }
  __syncthreads();

  if (t == 0) {
    double bt = 0.0;
    #pragma unroll
    for (int wv = 0; wv < 16; ++wv) bt += (double)sB[wv];
    double bce = bt / ((double)NB * HH * WW);
    double s = 0.0;
    for (int b = 0; b < NB; ++b) {
      double inter = (double)sI[b];
      double uni   = (double)sU[b];
      double wiou  = 1.0 - (inter + 1.0) / (uni - inter + 1.0);
      s += bce + wiou;   // wbce[b,c] == bce exactly (scalar * weit, renormalized)
    }
    out[0] = (float)(s / NB);
  }
}

extern "C" void kernel_launch(void* const* d_in, const int* in_sizes, int n_in,
                              void* d_out, int out_size, void* d_ws, size_t ws_size,
                              hipStream_t stream)
{
  const float* inp = (const float*)d_in[0];
  const float* tgt = (const float*)d_in[1];
  float* ws = (float*)d_ws;   // 3*8192 floats = 96 KB; fully written each launch

  wloss_main<<<NBLK, 256, 0, stream>>>(inp, tgt, ws);
  wloss_final<<<1, 1024, 0, stream>>>(ws, (float*)d_out);
}

// Round 3
// 329.965 us; speedup vs baseline: 1.2195x; 1.0054x over previous
//
#include <hip/hip_runtime.h>
#include <math.h>

#define HH 1024
#define WW 1024
#define NB 32
#define TS 64
#define IMG (HH * WW)
#define HROWS 94          // TS + 2*15
#define HSTR 68           // hrow LDS stride (68%32=4 spreads phase-1 write banks)
#define NT 4              // tiles per block
#define NBLK 2048         // 8192 tiles / NT
#define TILES_PER_IMG 256
#define NSLOT (NB * TILES_PER_IMG)

// LDS-only barrier: orders ds ops without draining vmcnt -> prefetch loads
// stay in flight across it (the __syncthreads vmcnt(0) drain was the stall).
#define RAW_BARRIER() asm volatile("s_waitcnt lgkmcnt(0)\n\ts_barrier" ::: "memory")

// ws layout (floats): bceP[8192] | intP[8192] | uniP[8192]

// Halo rows of tgt for one 64x64 tile: threads 0..187 = (row 0..93) x (half 0,1),
// each holds 64 floats (16 float4). OOB regions are whole-float4 aligned, so
// clamp-address + mask replaces the divergent edge path. Caller guards tid<188.
__device__ __forceinline__ void load_f(const float* __restrict__ tb,
                                       int r0, int c0, int tid, float fs[64])
{
  int rh = tid >> 1, h = tid & 1;
  int gr = r0 - 15 + rh;
  int grc = min(max(gr, 0), HH - 1);
  bool rowOK = ((unsigned)gr < (unsigned)HH);
  int cb = c0 + h * 32 - 16;
  const float* rowp = tb + (size_t)grc * WW;
  #pragma unroll
  for (int u = 0; u < 16; ++u) {
    int colb = cb + 4 * u;
    bool ok = rowOK && (colb >= 0) && (colb <= WW - 4);
    int colc = min(max(colb, 0), WW - 4);
    float4 q = *(const float4*)(rowp + colc);
    fs[4 * u + 0] = ok ? q.x : 0.f;
    fs[4 * u + 1] = ok ? q.y : 0.f;
    fs[4 * u + 2] = ok ? q.z : 0.f;
    fs[4 * u + 3] = ok ? q.w : 0.f;
  }
}

// inp pixels for one tile in phase-2 layout: thread = (col 0..63) x (rowgroup 0..3).
// Issued between phase 1 and the LDS-only barrier: the 16 loads stay in flight
// across s_barrier and land under the phase-2 vertical-sum preamble.
__device__ __forceinline__ void load_x(const float* __restrict__ ib,
                                       int r0, int c0, int tid, float xv[16])
{
  int c = tid & 63, rt0 = (tid >> 6) * 16;
  const float* p = ib + (size_t)(r0 + rt0) * WW + (c0 + c);
  #pragma unroll
  for (int j = 0; j < 16; ++j)
    xv[j] = __builtin_nontemporal_load(&p[(size_t)j * WW]);
}

// tgt center tile in phase-2 layout, prefetched to registers pre-barrier so the
// loss loop has ZERO global loads. These lines are L1/L2-hot (phase 1 just read
// them for fs), so this adds no HBM traffic -- it only moves the latency out of
// the compute loop and under the barrier + vs-preamble.
__device__ __forceinline__ void load_t(const float* __restrict__ tb,
                                       int r0, int c0, int tid, float tv[16])
{
  int c = tid & 63, rt0 = (tid >> 6) * 16;
  const float* p = tb + (size_t)(r0 + rt0) * WW + (c0 + c);
  #pragma unroll
  for (int j = 0; j < 16; ++j)
    tv[j] = p[(size_t)j * WW];
}

// TLP over ILP with a VGPR cap the live set fits: (256,6) spilled (round 1:
// 127MB scratch), (256,4) gives clean codegen (round 2: VGPR=60, 142us).
// Live across the barrier now: xv[16] + tv[16] (~80 VGPR peak, < 128 cap).
__global__ __launch_bounds__(256, 4) void wloss_main(
    const float* __restrict__ inp, const float* __restrict__ tgt,
    float* __restrict__ ws)
{
  __shared__ float hrow[HROWS * HSTR]; // 94*68*4 = 25568 B
  __shared__ float red[12];

  const int tid = threadIdx.x;
  const int k = blockIdx.x;            // 0..NBLK-1

  #pragma unroll
  for (int it = 0; it < NT; ++it) {
    const int tile = k + it * NBLK;
    const int b = tile >> 8, ty = (tile >> 4) & 15, tx = tile & 15;
    const int r0 = ty * TS, c0 = tx * TS;
    const float* tb = tgt + (size_t)b * IMG;

    // ---- phase 1: load halo + 31-wide horizontal sliding sums -> hrow ----
    // Write-as-you-go (float4 every 4 outputs): no out[32] array, fs dies here.
    if (tid < 188) {
      float fs[64];
      load_f(tb, r0, c0, tid, fs);
      int rh = tid >> 1, h = tid & 1;
      float a0 = 0.f, a1 = 0.f, a2 = 0.f, a3 = 0.f;
      #pragma unroll
      for (int i = 1; i <= 25; i += 4) {
        a0 += fs[i]; a1 += fs[i + 1]; a2 += fs[i + 2]; a3 += fs[i + 3];
      }
      float s = (a0 + a1) + (a2 + a3) + fs[29] + fs[30] + fs[31];
      float* hp = &hrow[rh * HSTR + h * 32];
      #pragma unroll
      for (int g = 0; g < 8; ++g) {
        float o0, o1, o2, o3;
        if (g == 0) { o0 = s; }
        else       { s += fs[4 * g + 31] - fs[4 * g]; o0 = s; }
        s += fs[4 * g + 32] - fs[4 * g + 1]; o1 = s;
        s += fs[4 * g + 33] - fs[4 * g + 2]; o2 = s;
        s += fs[4 * g + 34] - fs[4 * g + 3]; o3 = s;
        *(float4*)&hp[4 * g] = make_float4(o0, o1, o2, o3);
      }
    }

    // ---- issue ALL phase-2 global loads now; they ride across the barrier ----
    float xv[16], tv[16];
    load_x(inp + (size_t)b * IMG, r0, c0, tid, xv);
    load_t(tb, r0, c0, tid, tv);

    RAW_BARRIER();   // hrow write -> read; vmem stays in flight

    // ---- phase 2: vertical 31-slide + loss math (no global loads in loop) ----
    const int c = tid & 63;
    const int rt0 = (tid >> 6) * 16;
    float vs;
    {
      float a0 = 0.f, a1 = 0.f, a2 = 0.f, a3 = 0.f;
      #pragma unroll
      for (int kk = 0; kk < 28; kk += 4) {
        a0 += hrow[(rt0 + kk    ) * HSTR + c];
        a1 += hrow[(rt0 + kk + 1) * HSTR + c];
        a2 += hrow[(rt0 + kk + 2) * HSTR + c];
        a3 += hrow[(rt0 + kk + 3) * HSTR + c];
      }
      vs = (a0 + a1) + (a2 + a3)
         + hrow[(rt0 + 28) * HSTR + c] + hrow[(rt0 + 29) * HSTR + c]
         + hrow[(rt0 + 30) * HSTR + c];
    }

    float a_bce = 0.f, a_int = 0.f, a_uni = 0.f;
    #pragma unroll 8
    for (int j = 0; j < 16; ++j) {
      if (j) vs += hrow[(rt0 + j + 30) * HSTR + c] - hrow[(rt0 + j - 1) * HSTR + c];
      float t = tv[j];
      float x = xv[j];
      float w = fmaf(5.f, fabsf(vs * (1.f / 961.f) - t), 1.f);
      float ax  = fabsf(x);
      float e   = __expf(-ax);
      float inv = __fdividef(1.f, 1.f + e);
      float p   = (x >= 0.f) ? inv : e * inv;   // sigmoid from exp(-|x|)
      a_bce += fmaxf(x, 0.f) - x * t + __logf(1.f + e);
      a_int  = fmaf(p * t, w, a_int);
      a_uni  = fmaf(p + t, w, a_uni);
    }

    // ---- block reduction ----
    #pragma unroll
    for (int off = 32; off > 0; off >>= 1) {
      a_bce += __shfl_down(a_bce, off);
      a_int += __shfl_down(a_int, off);
      a_uni += __shfl_down(a_uni, off);
    }
    int wave = tid >> 6;
    if ((tid & 63) == 0) {
      red[wave * 3 + 0] = a_bce;
      red[wave * 3 + 1] = a_int;
      red[wave * 3 + 2] = a_uni;
    }
    RAW_BARRIER();   // red write -> read; also fences hrow reuse next iter
    if (tid == 0) {
      float sb = 0.f, si = 0.f, su = 0.f;
      #pragma unroll
      for (int wv = 0; wv < 4; ++wv) {
        sb += red[wv * 3 + 0];
        si += red[wv * 3 + 1];
        su += red[wv * 3 + 2];
      }
      ws[tile]             = sb;
      ws[NSLOT + tile]     = si;
      ws[2 * NSLOT + tile] = su;
    }
  }
}

__global__ __launch_bounds__(1024) void wloss_final(
    const float* __restrict__ ws, float* __restrict__ out)
{
  const float* bceP = ws;
  const float* intP = ws + NSLOT;
  const float* uniP = ws + 2 * NSLOT;
  __shared__ float sB[16];
  __shared__ float sI[NB], sU[NB];

  const int t = threadIdx.x;

  float bsum = 0.f;
  #pragma unroll
  for (int kk = 0; kk < 8; ++kk) bsum += bceP[t + kk * 1024];

  const int img = t >> 5, j = t & 31;
  const float* ip = intP + img * TILES_PER_IMG;
  const float* up = uniP + img * TILES_PER_IMG;
  float vi = 0.f, vu = 0.f;
  #pragma unroll
  for (int kk = 0; kk < 8; ++kk) { vi += ip[j + 32 * kk]; vu += up[j + 32 * kk]; }

  #pragma unroll
  for (int off = 32; off > 0; off >>= 1) bsum += __shfl_down(bsum, off, 64);
  #pragma unroll
  for (int off = 16; off > 0; off >>= 1) {
    vi += __shfl_down(vi, off, 32);
    vu += __shfl_down(vu, off, 32);
  }
  if ((t & 63) == 0) sB[t >> 6] = bsum;
  if (j == 0) { sI[img] = vi; sU[img] = vu; }
  __syncthreads();

  if (t == 0) {
    double bt = 0.0;
    #pragma unroll
    for (int wv = 0; wv < 16; ++wv) bt += (double)sB[wv];
    double bce = bt / ((double)NB * HH * WW);
    double s = 0.0;
    for (int b = 0; b < NB; ++b) {
      double inter = (double)sI[b];
      double uni   = (double)sU[b];
      double wiou  = 1.0 - (inter + 1.0) / (uni - inter + 1.0);
      s += bce + wiou;   // wbce[b,c] == bce exactly (scalar * weit, renormalized)
    }
    out[0] = (float)(s / NB);
  }
}

extern "C" void kernel_launch(void* const* d_in, const int* in_sizes, int n_in,
                              void* d_out, int out_size, void* d_ws, size_t ws_size,
                              hipStream_t stream)
{
  const float* inp = (const float*)d_in[0];
  const float* tgt = (const float*)d_in[1];
  float* ws = (float*)d_ws;   // 3*8192 floats = 96 KB; fully written each launch

  wloss_main<<<NBLK, 256, 0, stream>>>(inp, tgt, ws);
  wloss_final<<<1, 1024, 0, stream>>>(ws, (float*)d_out);
}

// Round 4
// 307.534 us; speedup vs baseline: 1.3085x; 1.0729x over previous
//
#include <hip/hip_runtime.h>
#include <math.h>

#define HH 1024
#define WW 1024
#define NB 32
#define TS 64
#define IMG (HH * WW)
#define HROWS 94          // TS + 2*15
#define HSTR 68           // hrow LDS stride (68%32=4 spreads phase-1 write banks)
#define NT 4              // tiles per block
#define NBLK 2048         // 8192 tiles / NT
#define TILES_PER_IMG 256
#define NSLOT (NB * TILES_PER_IMG)

// LDS-only barrier: orders ds ops without draining vmcnt -> prefetch loads
// stay in flight across it (the __syncthreads vmcnt(0) drain was the stall).
#define RAW_BARRIER() asm volatile("s_waitcnt lgkmcnt(0)\n\ts_barrier" ::: "memory")

// ws layout (floats): bceP[8192] | intP[8192] | uniP[8192]

// Halo rows of tgt for one 64x64 tile: threads 0..187 = (row 0..93) x (half 0,1),
// each holds 64 floats (16 float4). Masked path for edge tiles only.
__device__ __forceinline__ void load_f_edge(const float* __restrict__ tb,
                                            int r0, int c0, int tid, float fs[64])
{
  int rh = tid >> 1, h = tid & 1;
  int gr = r0 - 15 + rh;
  int grc = min(max(gr, 0), HH - 1);
  bool rowOK = ((unsigned)gr < (unsigned)HH);
  int cb = c0 + h * 32 - 16;
  const float* rowp = tb + (size_t)grc * WW;
  #pragma unroll
  for (int u = 0; u < 16; ++u) {
    int colb = cb + 4 * u;
    bool ok = rowOK && (colb >= 0) && (colb <= WW - 4);
    int colc = min(max(colb, 0), WW - 4);
    float4 q = *(const float4*)(rowp + colc);
    fs[4 * u + 0] = ok ? q.x : 0.f;
    fs[4 * u + 1] = ok ? q.y : 0.f;
    fs[4 * u + 2] = ok ? q.z : 0.f;
    fs[4 * u + 3] = ok ? q.w : 0.f;
  }
}

// Interior tiles (ty,tx in [1,14]: 196/256 of tiles): whole halo is in-bounds.
// One 64-bit base, 16 imm-offset float4 loads (240B max fits the 13-bit imm),
// zero cndmask/clamp VALU.
__device__ __forceinline__ void load_f_fast(const float* __restrict__ tb,
                                            int r0, int c0, int tid, float fs[64])
{
  int rh = tid >> 1, h = tid & 1;
  const float* rowp = tb + (size_t)(r0 - 15 + rh) * WW + (c0 + h * 32 - 16);
  #pragma unroll
  for (int u = 0; u < 16; ++u) {
    float4 q = *(const float4*)(rowp + 4 * u);
    fs[4 * u + 0] = q.x;
    fs[4 * u + 1] = q.y;
    fs[4 * u + 2] = q.z;
    fs[4 * u + 3] = q.w;
  }
}

// inp pixels for one tile in phase-2 layout: thread = (col 0..63) x (rowgroup 0..3).
// Issued between phase 1 and the LDS-only barrier: the 16 loads stay in flight
// across s_barrier and land under the phase-2 vertical-sum preamble.
__device__ __forceinline__ void load_x(const float* __restrict__ ib,
                                       int r0, int c0, int tid, float xv[16])
{
  int c = tid & 63, rt0 = (tid >> 6) * 16;
  const float* p = ib + (size_t)(r0 + rt0) * WW + (c0 + c);
  #pragma unroll
  for (int j = 0; j < 16; ++j)
    xv[j] = __builtin_nontemporal_load(&p[(size_t)j * WW]);
}

// tgt center tile in phase-2 layout, prefetched to registers pre-barrier so the
// loss loop has ZERO global loads (L1/L2-hot lines from phase 1).
__device__ __forceinline__ void load_t(const float* __restrict__ tb,
                                       int r0, int c0, int tid, float tv[16])
{
  int c = tid & 63, rt0 = (tid >> 6) * 16;
  const float* p = tb + (size_t)(r0 + rt0) * WW + (c0 + c);
  #pragma unroll
  for (int j = 0; j < 16; ++j)
    tv[j] = p[(size_t)j * WW];
}

// VGPR-cap history (empirical: effective cap = 256/minwaves on this compiler):
//   (256,3) -> cap 85, used 84 (r0)   (256,4) -> cap 64, used 56-60 (r2/r3)
//   (256,6) -> cap 42, SPILLED to 40 + 127MB scratch (r1 — never again)
// (256,2) -> cap 128: free the scheduler; residency floor stays >= measured ~12 waves.
__global__ __launch_bounds__(256, 2) void wloss_main(
    const float* __restrict__ inp, const float* __restrict__ tgt,
    float* __restrict__ ws)
{
  __shared__ float hrow[HROWS * HSTR]; // 94*68*4 = 25568 B
  __shared__ float red[12];

  const int tid = threadIdx.x;
  const int k = blockIdx.x;            // 0..NBLK-1

  #pragma unroll
  for (int it = 0; it < NT; ++it) {
    const int tile = k + it * NBLK;
    const int b = tile >> 8, ty = (tile >> 4) & 15, tx = tile & 15;
    const int r0 = ty * TS, c0 = tx * TS;
    const float* tb = tgt + (size_t)b * IMG;
    const bool interior = ((unsigned)(ty - 1) < 14u) && ((unsigned)(tx - 1) < 14u);

    // ---- phase 1: load halo + 31-wide horizontal sliding sums -> hrow ----
    // Write-as-you-go (float4 every 4 outputs): no out[32] array, fs dies here.
    if (tid < 188) {
      float fs[64];
      if (interior) load_f_fast(tb, r0, c0, tid, fs);   // block-uniform branch
      else          load_f_edge(tb, r0, c0, tid, fs);
      int rh = tid >> 1, h = tid & 1;
      float a0 = 0.f, a1 = 0.f, a2 = 0.f, a3 = 0.f;
      #pragma unroll
      for (int i = 1; i <= 25; i += 4) {
        a0 += fs[i]; a1 += fs[i + 1]; a2 += fs[i + 2]; a3 += fs[i + 3];
      }
      float s = (a0 + a1) + (a2 + a3) + fs[29] + fs[30] + fs[31];
      float* hp = &hrow[rh * HSTR + h * 32];
      #pragma unroll
      for (int g = 0; g < 8; ++g) {
        float o0, o1, o2, o3;
        if (g == 0) { o0 = s; }
        else       { s += fs[4 * g + 31] - fs[4 * g]; o0 = s; }
        s += fs[4 * g + 32] - fs[4 * g + 1]; o1 = s;
        s += fs[4 * g + 33] - fs[4 * g + 2]; o2 = s;
        s += fs[4 * g + 34] - fs[4 * g + 3]; o3 = s;
        *(float4*)&hp[4 * g] = make_float4(o0, o1, o2, o3);
      }
    }

    // ---- issue ALL phase-2 global loads now; they ride across the barrier ----
    float xv[16], tv[16];
    load_x(inp + (size_t)b * IMG, r0, c0, tid, xv);
    load_t(tb, r0, c0, tid, tv);

    RAW_BARRIER();   // hrow write -> read; vmem stays in flight

    // ---- phase 2: vertical 31-slide + loss math (no global loads in loop) ----
    const int c = tid & 63;
    const int rt0 = (tid >> 6) * 16;
    float vs;
    {
      float a0 = 0.f, a1 = 0.f, a2 = 0.f, a3 = 0.f;
      #pragma unroll
      for (int kk = 0; kk < 28; kk += 4) {
        a0 += hrow[(rt0 + kk    ) * HSTR + c];
        a1 += hrow[(rt0 + kk + 1) * HSTR + c];
        a2 += hrow[(rt0 + kk + 2) * HSTR + c];
        a3 += hrow[(rt0 + kk + 3) * HSTR + c];
      }
      vs = (a0 + a1) + (a2 + a3)
         + hrow[(rt0 + 28) * HSTR + c] + hrow[(rt0 + 29) * HSTR + c]
         + hrow[(rt0 + 30) * HSTR + c];
    }

    float a_bce = 0.f, a_int = 0.f, a_uni = 0.f;
    #pragma unroll
    for (int j = 0; j < 16; ++j) {
      if (j) vs += hrow[(rt0 + j + 30) * HSTR + c] - hrow[(rt0 + j - 1) * HSTR + c];
      float t = tv[j];
      float x = xv[j];
      float w = fmaf(5.f, fabsf(vs * (1.f / 961.f) - t), 1.f);
      float ax  = fabsf(x);
      float e   = __expf(-ax);
      float inv = __fdividef(1.f, 1.f + e);
      float p   = (x >= 0.f) ? inv : e * inv;   // sigmoid from exp(-|x|)
      a_bce += fmaxf(x, 0.f) - x * t + __logf(1.f + e);
      a_int  = fmaf(p * t, w, a_int);
      a_uni  = fmaf(p + t, w, a_uni);
    }

    // ---- block reduction ----
    #pragma unroll
    for (int off = 32; off > 0; off >>= 1) {
      a_bce += __shfl_down(a_bce, off);
      a_int += __shfl_down(a_int, off);
      a_uni += __shfl_down(a_uni, off);
    }
    int wave = tid >> 6;
    if ((tid & 63) == 0) {
      red[wave * 3 + 0] = a_bce;
      red[wave * 3 + 1] = a_int;
      red[wave * 3 + 2] = a_uni;
    }
    RAW_BARRIER();   // red write -> read; also fences hrow reuse next iter
    if (tid == 0) {
      float sb = 0.f, si = 0.f, su = 0.f;
      #pragma unroll
      for (int wv = 0; wv < 4; ++wv) {
        sb += red[wv * 3 + 0];
        si += red[wv * 3 + 1];
        su += red[wv * 3 + 2];
      }
      ws[tile]             = sb;
      ws[NSLOT + tile]     = si;
      ws[2 * NSLOT + tile] = su;
    }
  }
}

__global__ __launch_bounds__(1024) void wloss_final(
    const float* __restrict__ ws, float* __restrict__ out)
{
  const float* bceP = ws;
  const float* intP = ws + NSLOT;
  const float* uniP = ws + 2 * NSLOT;
  __shared__ float sB[16];
  __shared__ float sI[NB], sU[NB];

  const int t = threadIdx.x;

  float bsum = 0.f;
  #pragma unroll
  for (int kk = 0; kk < 8; ++kk) bsum += bceP[t + kk * 1024];

  const int img = t >> 5, j = t & 31;
  const float* ip = intP + img * TILES_PER_IMG;
  const float* up = uniP + img * TILES_PER_IMG;
  float vi = 0.f, vu = 0.f;
  #pragma unroll
  for (int kk = 0; kk < 8; ++kk) { vi += ip[j + 32 * kk]; vu += up[j + 32 * kk]; }

  #pragma unroll
  for (int off = 32; off > 0; off >>= 1) bsum += __shfl_down(bsum, off, 64);
  #pragma unroll
  for (int off = 16; off > 0; off >>= 1) {
    vi += __shfl_down(vi, off, 32);
    vu += __shfl_down(vu, off, 32);
  }
  if ((t & 63) == 0) sB[t >> 6] = bsum;
  if (j == 0) { sI[img] = vi; sU[img] = vu; }
  __syncthreads();

  if (t == 0) {
    double bt = 0.0;
    #pragma unroll
    for (int wv = 0; wv < 16; ++wv) bt += (double)sB[wv];
    double bce = bt / ((double)NB * HH * WW);
    double s = 0.0;
    for (int b = 0; b < NB; ++b) {
      double inter = (double)sI[b];
      double uni   = (double)sU[b];
      double wiou  = 1.0 - (inter + 1.0) / (uni - inter + 1.0);
      s += bce + wiou;   // wbce[b,c] == bce exactly (scalar * weit, renormalized)
    }
    out[0] = (float)(s / NB);
  }
}

extern "C" void kernel_launch(void* const* d_in, const int* in_sizes, int n_in,
                              void* d_out, int out_size, void* d_ws, size_t ws_size,
                              hipStream_t stream)
{
  const float* inp = (const float*)d_in[0];
  const float* tgt = (const float*)d_in[1];
  float* ws = (float*)d_ws;   // 3*8192 floats = 96 KB; fully written each launch

  wloss_main<<<NBLK, 256, 0, stream>>>(inp, tgt, ws);
  wloss_final<<<1, 1024, 0, stream>>>(ws, (float*)d_out);
}

// Round 5
// 305.008 us; speedup vs baseline: 1.3193x; 1.0083x over previous
//
#include <hip/hip_runtime.h>
#include <math.h>

#define HH 1024
#define WW 1024
#define NB 32
#define TS 64
#define IMG (HH * WW)
#define HROWS 94          // TS + 2*15
#define HSTR 68           // hrow LDS stride (68%32=4 spreads phase-1 write banks)
#define NT 4              // tiles per block
#define NBLK 2048         // 8192 tiles / NT
#define TILES_PER_IMG 256
#define NSLOT (NB * TILES_PER_IMG)

// LDS-only barrier: orders ds ops without draining vmcnt -> prefetch loads
// stay in flight across it (the __syncthreads vmcnt(0) drain was the stall).
#define RAW_BARRIER() asm volatile("s_waitcnt lgkmcnt(0)\n\ts_barrier" ::: "memory")

// ws layout (floats): bceP[8192] | intP[8192] | uniP[8192]

// Halo rows of tgt for one 64x64 tile: threads 0..187 = (row 0..93) x (half 0,1),
// each holds 64 floats (16 float4). Masked path for edge tiles only.
__device__ __forceinline__ void load_f_edge(const float* __restrict__ tb,
                                            int r0, int c0, int tid, float fs[64])
{
  int rh = tid >> 1, h = tid & 1;
  int gr = r0 - 15 + rh;
  int grc = min(max(gr, 0), HH - 1);
  bool rowOK = ((unsigned)gr < (unsigned)HH);
  int cb = c0 + h * 32 - 16;
  const float* rowp = tb + (size_t)grc * WW;
  #pragma unroll
  for (int u = 0; u < 16; ++u) {
    int colb = cb + 4 * u;
    bool ok = rowOK && (colb >= 0) && (colb <= WW - 4);
    int colc = min(max(colb, 0), WW - 4);
    float4 q = *(const float4*)(rowp + colc);
    fs[4 * u + 0] = ok ? q.x : 0.f;
    fs[4 * u + 1] = ok ? q.y : 0.f;
    fs[4 * u + 2] = ok ? q.z : 0.f;
    fs[4 * u + 3] = ok ? q.w : 0.f;
  }
}

// Interior tiles (ty,tx in [1,14]: 196/256 of tiles): whole halo in-bounds.
// One 64-bit base, 16 imm-offset float4 loads, zero cndmask/clamp VALU.
// (round 4: this fast path was the 142->118us win)
__device__ __forceinline__ void load_f_fast(const float* __restrict__ tb,
                                            int r0, int c0, int tid, float fs[64])
{
  int rh = tid >> 1, h = tid & 1;
  const float* rowp = tb + (size_t)(r0 - 15 + rh) * WW + (c0 + h * 32 - 16);
  #pragma unroll
  for (int u = 0; u < 16; ++u) {
    float4 q = *(const float4*)(rowp + 4 * u);
    fs[4 * u + 0] = q.x;
    fs[4 * u + 1] = q.y;
    fs[4 * u + 2] = q.z;
    fs[4 * u + 3] = q.w;
  }
}

// inp pixels for one tile in phase-2 layout: thread = (col 0..63) x (rowgroup 0..3).
// Issued between phase 1 and the LDS-only barrier: the 16 loads stay in flight
// across s_barrier and land under the phase-2 hr[] preload.
__device__ __forceinline__ void load_x(const float* __restrict__ ib,
                                       int r0, int c0, int tid, float xv[16])
{
  int c = tid & 63, rt0 = (tid >> 6) * 16;
  const float* p = ib + (size_t)(r0 + rt0) * WW + (c0 + c);
  #pragma unroll
  for (int j = 0; j < 16; ++j)
    xv[j] = __builtin_nontemporal_load(&p[(size_t)j * WW]);
}

// tgt center tile in phase-2 layout, prefetched to registers pre-barrier
// (L1/L2-hot lines from phase 1).
__device__ __forceinline__ void load_t(const float* __restrict__ tb,
                                       int r0, int c0, int tid, float tv[16])
{
  int c = tid & 63, rt0 = (tid >> 6) * 16;
  const float* p = tb + (size_t)(r0 + rt0) * WW + (c0 + c);
  #pragma unroll
  for (int j = 0; j < 16; ++j)
    tv[j] = p[(size_t)j * WW];
}

// VGPR-cap history (empirical cap = 256/minwaves): (256,3)->84, (256,4)->56-60,
// (256,6)->SPILL (r1, 127MB scratch). (256,2) -> cap 128. The allocator won't
// use headroom unless values are NAMED in source (r4: cap 128, still chose 52)
// -> hr[46] below forces the phase-2 column into registers.
__global__ __launch_bounds__(256, 2) void wloss_main(
    const float* __restrict__ inp, const float* __restrict__ tgt,
    float* __restrict__ ws)
{
  __shared__ float hrow[HROWS * HSTR]; // 94*68*4 = 25568 B
  __shared__ float red[12];

  const int tid = threadIdx.x;
  const int k = blockIdx.x;            // 0..NBLK-1

  #pragma unroll
  for (int it = 0; it < NT; ++it) {
    const int tile = k + it * NBLK;
    const int b = tile >> 8, ty = (tile >> 4) & 15, tx = tile & 15;
    const int r0 = ty * TS, c0 = tx * TS;
    const float* tb = tgt + (size_t)b * IMG;
    const bool interior = ((unsigned)(ty - 1) < 14u) && ((unsigned)(tx - 1) < 14u);

    // ---- phase 1: load halo + 31-wide horizontal sliding sums -> hrow ----
    if (tid < 188) {
      float fs[64];
      if (interior) load_f_fast(tb, r0, c0, tid, fs);   // block-uniform branch
      else          load_f_edge(tb, r0, c0, tid, fs);
      int rh = tid >> 1, h = tid & 1;
      float a0 = 0.f, a1 = 0.f, a2 = 0.f, a3 = 0.f;
      #pragma unroll
      for (int i = 1; i <= 25; i += 4) {
        a0 += fs[i]; a1 += fs[i + 1]; a2 += fs[i + 2]; a3 += fs[i + 3];
      }
      float s = (a0 + a1) + (a2 + a3) + fs[29] + fs[30] + fs[31];
      float* hp = &hrow[rh * HSTR + h * 32];
      #pragma unroll
      for (int g = 0; g < 8; ++g) {
        float o0, o1, o2, o3;
        if (g == 0) { o0 = s; }
        else       { s += fs[4 * g + 31] - fs[4 * g]; o0 = s; }
        s += fs[4 * g + 32] - fs[4 * g + 1]; o1 = s;
        s += fs[4 * g + 33] - fs[4 * g + 2]; o2 = s;
        s += fs[4 * g + 34] - fs[4 * g + 3]; o3 = s;
        *(float4*)&hp[4 * g] = make_float4(o0, o1, o2, o3);
      }
    }

    // ---- issue ALL phase-2 global loads now; they ride across the barrier ----
    float xv[16], tv[16];
    load_x(inp + (size_t)b * IMG, r0, c0, tid, xv);
    load_t(tb, r0, c0, tid, tv);

    RAW_BARRIER();   // hrow write -> read; vmem stays in flight

    // ---- phase 2: preload the whole hrow column into registers ----
    // 46 independent ds_read issued back-to-back (one lgkmcnt drain), instead
    // of 61 reads interleaved into the vs dependency chain (the r4 stall:
    // 52-reg schedule couldn't hoist, paying ~LDS latency per unroll step).
    // Also removes 15 redundant re-reads. Live set ~95 regs < 128 cap.
    const int c = tid & 63;
    const int rt0 = (tid >> 6) * 16;
    float hr[46];
    {
      const float* hp = &hrow[rt0 * HSTR + c];
      #pragma unroll
      for (int r = 0; r < 46; ++r)
        hr[r] = hp[(size_t)r * HSTR];
    }

    float vs;
    {
      float a0 = 0.f, a1 = 0.f, a2 = 0.f, a3 = 0.f;
      #pragma unroll
      for (int kk = 0; kk < 28; kk += 4) {
        a0 += hr[kk]; a1 += hr[kk + 1]; a2 += hr[kk + 2]; a3 += hr[kk + 3];
      }
      vs = (a0 + a1) + (a2 + a3) + hr[28] + hr[29] + hr[30];
    }

    // ---- loss math: zero memory ops in the loop ----
    float a_bce = 0.f, a_int = 0.f, a_uni = 0.f;
    #pragma unroll
    for (int j = 0; j < 16; ++j) {
      if (j) vs += hr[j + 30] - hr[j - 1];
      float t = tv[j];
      float x = xv[j];
      float w = fmaf(5.f, fabsf(vs * (1.f / 961.f) - t), 1.f);
      float ax  = fabsf(x);
      float e   = __expf(-ax);
      float inv = __fdividef(1.f, 1.f + e);
      float p   = (x >= 0.f) ? inv : e * inv;   // sigmoid from exp(-|x|)
      a_bce += fmaxf(x, 0.f) - x * t + __logf(1.f + e);
      a_int  = fmaf(p * t, w, a_int);
      a_uni  = fmaf(p + t, w, a_uni);
    }

    // ---- block reduction ----
    #pragma unroll
    for (int off = 32; off > 0; off >>= 1) {
      a_bce += __shfl_down(a_bce, off);
      a_int += __shfl_down(a_int, off);
      a_uni += __shfl_down(a_uni, off);
    }
    int wave = tid >> 6;
    if ((tid & 63) == 0) {
      red[wave * 3 + 0] = a_bce;
      red[wave * 3 + 1] = a_int;
      red[wave * 3 + 2] = a_uni;
    }
    RAW_BARRIER();   // red write -> read; also fences hrow reuse next iter
    if (tid == 0) {
      float sb = 0.f, si = 0.f, su = 0.f;
      #pragma unroll
      for (int wv = 0; wv < 4; ++wv) {
        sb += red[wv * 3 + 0];
        si += red[wv * 3 + 1];
        su += red[wv * 3 + 2];
      }
      ws[tile]             = sb;
      ws[NSLOT + tile]     = si;
      ws[2 * NSLOT + tile] = su;
    }
  }
}

__global__ __launch_bounds__(1024) void wloss_final(
    const float* __restrict__ ws, float* __restrict__ out)
{
  const float* bceP = ws;
  const float* intP = ws + NSLOT;
  const float* uniP = ws + 2 * NSLOT;
  __shared__ float sB[16];
  __shared__ float sI[NB], sU[NB];

  const int t = threadIdx.x;

  float bsum = 0.f;
  #pragma unroll
  for (int kk = 0; kk < 8; ++kk) bsum += bceP[t + kk * 1024];

  const int img = t >> 5, j = t & 31;
  const float* ip = intP + img * TILES_PER_IMG;
  const float* up = uniP + img * TILES_PER_IMG;
  float vi = 0.f, vu = 0.f;
  #pragma unroll
  for (int kk = 0; kk < 8; ++kk) { vi += ip[j + 32 * kk]; vu += up[j + 32 * kk]; }

  #pragma unroll
  for (int off = 32; off > 0; off >>= 1) bsum += __shfl_down(bsum, off, 64);
  #pragma unroll
  for (int off = 16; off > 0; off >>= 1) {
    vi += __shfl_down(vi, off, 32);
    vu += __shfl_down(vu, off, 32);
  }
  if ((t & 63) == 0) sB[t >> 6] = bsum;
  if (j == 0) { sI[img] = vi; sU[img] = vu; }
  __syncthreads();

  if (t == 0) {
    double bt = 0.0;
    #pragma unroll
    for (int wv = 0; wv < 16; ++wv) bt += (double)sB[wv];
    double bce = bt / ((double)NB * HH * WW);
    double s = 0.0;
    for (int b = 0; b < NB; ++b) {
      double inter = (double)sI[b];
      double uni   = (double)sU[b];
      double wiou  = 1.0 - (inter + 1.0) / (uni - inter + 1.0);
      s += bce + wiou;   // wbce[b,c] == bce exactly (scalar * weit, renormalized)
    }
    out[0] = (float)(s / NB);
  }
}

extern "C" void kernel_launch(void* const* d_in, const int* in_sizes, int n_in,
                              void* d_out, int out_size, void* d_ws, size_t ws_size,
                              hipStream_t stream)
{
  const float* inp = (const float*)d_in[0];
  const float* tgt = (const float*)d_in[1];
  float* ws = (float*)d_ws;   // 3*8192 floats = 96 KB; fully written each launch

  wloss_main<<<NBLK, 256, 0, stream>>>(inp, tgt, ws);
  wloss_final<<<1, 1024, 0, stream>>>(ws, (float*)d_out);
}